// Round 1
// baseline (127.275 us; speedup 1.0000x reference)
//
#include <hip/hip_runtime.h>

typedef __attribute__((ext_vector_type(4))) float f32x4;
typedef __attribute__((ext_vector_type(8))) short s16x8;
typedef __attribute__((ext_vector_type(4))) unsigned short u16x4;

#define DEVFN static __device__ __forceinline__

DEVFN unsigned short f2bf(float f) {
  union { float f; unsigned int u; } v; v.f = f;
  unsigned int u = v.u;
  u += 0x7fffu + ((u >> 16) & 1u);   // RNE
  return (unsigned short)(u >> 16);
}
DEVFN float bf2f(unsigned short s) {
  union { unsigned int u; float f; } v; v.u = ((unsigned int)s) << 16;
  return v.f;
}

// problem dims
#define Mm 32768   // B*S
#define Dd 1024
#define Hh 256
#define CC 512

// workspace layout (bytes / float offsets)
#define DG_OFF 0
#define DB_OFF 2048
#define UG_OFF 4096
#define UB_OFF 12288
#define WDT_BYTE 81920
#define WUT_BYTE 606208
#define ACT_BYTE 1130496

// ---------- tiny coefficient GEMMs: conditions[8,512] @ {gamma,beta} ----------
__global__ void coef_kernel(const float* __restrict__ cond,
                            const float* __restrict__ dgm, const float* __restrict__ dbt,
                            const float* __restrict__ ugm, const float* __restrict__ ubt,
                            float* __restrict__ coef) {
  int gid = blockIdx.x * 256 + threadIdx.x;
  const float* src; float* dst; int b, col, ncol;
  if (gid < 2048)       { src = dgm; dst = coef + DG_OFF; int g = gid;         b = g >> 8;  col = g & 255;  ncol = 256; }
  else if (gid < 4096)  { src = dbt; dst = coef + DB_OFF; int g = gid - 2048;  b = g >> 8;  col = g & 255;  ncol = 256; }
  else if (gid < 12288) { src = ugm; dst = coef + UG_OFF; int g = gid - 4096;  b = g >> 10; col = g & 1023; ncol = 1024; }
  else                  { src = ubt; dst = coef + UB_OFF; int g = gid - 12288; b = g >> 10; col = g & 1023; ncol = 1024; }
  float acc = 0.f;
  const float* cp = cond + b * CC;
  for (int c = 0; c < CC; ++c) acc = fmaf(cp[c], src[c * ncol + col], acc);
  dst[b * ncol + col] = acc;
}

// ---------- transpose + f32->bf16 convert: out[c][r] = in[r][c] ----------
__global__ void transpose_kernel(const float* __restrict__ in, unsigned short* __restrict__ outp,
                                 int R, int Cdim) {
  __shared__ float tile[32][33];
  int nTc = Cdim >> 5;
  int r0 = (blockIdx.x / nTc) << 5;
  int c0 = (blockIdx.x % nTc) << 5;
  int tr = threadIdx.x >> 5, tc = threadIdx.x & 31;
#pragma unroll
  for (int i = 0; i < 4; ++i)
    tile[tr + i * 8][tc] = in[(size_t)(r0 + tr + i * 8) * Cdim + c0 + tc];
  __syncthreads();
#pragma unroll
  for (int i = 0; i < 4; ++i) {
    int c = tr + i * 8;
    outp[(size_t)(c0 + c) * R + r0 + tc] = f2bf(tile[tc][c]);
  }
}

// ---------- GEMM1: act = relu(dg ∘ (X @ Wd) + db ∘ rowsum(X)) ----------
// X [32768][1024] f32, WdT [256][1024] bf16 (= Wd^T), act [32768][256] bf16
// BM=64, N=256 (full), BK=64; 256 threads = 4 waves (2m x 2n), wave tile 32x128
__global__ __launch_bounds__(256, 2)
void gemm1_kernel(const float* __restrict__ X, const unsigned short* __restrict__ WdT,
                  const float* __restrict__ coef, unsigned short* __restrict__ act) {
  __shared__ __align__(16) char Xs[64 * 128];    // [row][64 bf16] swizzled
  __shared__ __align__(16) char Ws[256 * 128];   // [n][64 bf16] swizzled
  __shared__ float dgs[256], dbs[256], hsum[64];

  const int tid = threadIdx.x;
  const int row0 = blockIdx.x * 64;
  const int bidx = row0 >> 12;

  dgs[tid] = coef[DG_OFF + bidx * 256 + tid];
  dbs[tid] = coef[DB_OFF + bidx * 256 + tid];

  // X staging: thread covers rows (tid>>4)+j*16, cols (tid&15)*4..+3
  const int rowg = tid >> 4, cl = tid & 15;
  const float* xptr = X + (size_t)(row0 + rowg) * Dd + cl * 4;
  int xw[4];
#pragma unroll
  for (int j = 0; j < 4; ++j) {
    int r = rowg + j * 16;
    xw[j] = r * 128 + ((((cl * 4) >> 3) ^ (r & 7)) << 4) + ((cl & 1) ? 8 : 0);
  }
  // W staging: thread covers row (tid>>3)+it*32, granule tid&7
  const int wrow = tid >> 3, wg = tid & 7;
  const unsigned short* wptr = WdT + (size_t)wrow * Dd + wg * 8;
  int wwr[8];
#pragma unroll
  for (int it = 0; it < 8; ++it) {
    int n = wrow + it * 32;
    wwr[it] = n * 128 + ((wg ^ (n & 7)) << 4);
  }

  // compute-side addresses
  const int lane = tid & 63, wave = tid >> 6;
  const int wm = wave >> 1, wn = wave & 1;
  const int lr = lane & 15, lq = lane >> 4;
  int ard[2][2];
#pragma unroll
  for (int mf = 0; mf < 2; ++mf)
#pragma unroll
    for (int kf = 0; kf < 2; ++kf) {
      int r = wm * 32 + mf * 16 + lr;
      ard[mf][kf] = r * 128 + (((kf * 4 + lq) ^ (r & 7)) << 4);
    }
  int brd[8][2];
#pragma unroll
  for (int nf = 0; nf < 8; ++nf)
#pragma unroll
    for (int kf = 0; kf < 2; ++kf) {
      int n = wn * 128 + nf * 16 + lr;
      brd[nf][kf] = n * 128 + (((kf * 4 + lq) ^ (n & 7)) << 4);
    }

  f32x4 acc[2][8] = {};
  float hacc[4] = {0.f, 0.f, 0.f, 0.f};

  for (int ks = 0; ks < 16; ++ks) {
    __syncthreads();
    // stage X (f32 -> bf16) + accumulate row sums
#pragma unroll
    for (int j = 0; j < 4; ++j) {
      f32x4 v = *(const f32x4*)(xptr + (size_t)j * 16 * Dd);
      hacc[j] += v[0] + v[1] + v[2] + v[3];
      u16x4 p; p[0] = f2bf(v[0]); p[1] = f2bf(v[1]); p[2] = f2bf(v[2]); p[3] = f2bf(v[3]);
      *(u16x4*)(Xs + xw[j]) = p;
    }
    xptr += 64;
    // stage W
#pragma unroll
    for (int it = 0; it < 8; ++it) {
      s16x8 w = *(const s16x8*)(wptr + (size_t)it * 32 * Dd);
      *(s16x8*)(Ws + wwr[it]) = w;
    }
    wptr += 64;
    __syncthreads();
    // MFMA
#pragma unroll
    for (int kf = 0; kf < 2; ++kf) {
      s16x8 a0 = *(const s16x8*)(Xs + ard[0][kf]);
      s16x8 a1 = *(const s16x8*)(Xs + ard[1][kf]);
#pragma unroll
      for (int nf = 0; nf < 8; ++nf) {
        s16x8 bb = *(const s16x8*)(Ws + brd[nf][kf]);
        acc[0][nf] = __builtin_amdgcn_mfma_f32_16x16x32_bf16(a0, bb, acc[0][nf], 0, 0, 0);
        acc[1][nf] = __builtin_amdgcn_mfma_f32_16x16x32_bf16(a1, bb, acc[1][nf], 0, 0, 0);
      }
    }
  }

  // reduce per-row sums (16 lanes per row group share a row)
#pragma unroll
  for (int j = 0; j < 4; ++j) {
    float s = hacc[j];
    s += __shfl_xor(s, 1); s += __shfl_xor(s, 2); s += __shfl_xor(s, 4); s += __shfl_xor(s, 8);
    if (lr == 0) hsum[rowg + j * 16] = s;
  }
  __syncthreads();

  // epilogue: modulation + relu -> bf16
#pragma unroll
  for (int mf = 0; mf < 2; ++mf) {
    int rbase = wm * 32 + mf * 16 + lq * 4;
#pragma unroll
    for (int nf = 0; nf < 8; ++nf) {
      int h = wn * 128 + nf * 16 + lr;
      float dgv = dgs[h], dbv = dbs[h];
#pragma unroll
      for (int j = 0; j < 4; ++j) {
        float v = acc[mf][nf][j] * dgv + dbv * hsum[rbase + j];
        v = fmaxf(v, 0.f);
        act[(size_t)(row0 + rbase + j) * Hh + h] = f2bf(v);
      }
    }
  }
}

// ---------- GEMM2: out = ug ∘ (act @ Wu) + ub ∘ rowsum(act) + X ----------
// act [32768][256] bf16, WuT [1024][256] bf16 (= Wu^T), out [32768][1024] f32
// BM=64, BN=256, BK=64; grid (512, 4)
__global__ __launch_bounds__(256, 2)
void gemm2_kernel(const unsigned short* __restrict__ act, const unsigned short* __restrict__ WuT,
                  const float* __restrict__ coef, const float* __restrict__ X,
                  float* __restrict__ out) {
  __shared__ __align__(16) char As[64 * 128];
  __shared__ __align__(16) char Ws[256 * 128];
  __shared__ float ugs[256], ubs[256], asum[64];

  const int tid = threadIdx.x;
  const int row0 = blockIdx.x * 64;
  const int n0 = blockIdx.y * 256;
  const int bidx = row0 >> 12;

  ugs[tid] = coef[UG_OFF + bidx * 1024 + n0 + tid];
  ubs[tid] = coef[UB_OFF + bidx * 1024 + n0 + tid];

  const int rowg = tid >> 4, cl = tid & 15;
  const unsigned short* aptr = act + (size_t)(row0 + rowg) * Hh + cl * 4;
  int aw[4];
#pragma unroll
  for (int j = 0; j < 4; ++j) {
    int r = rowg + j * 16;
    aw[j] = r * 128 + ((((cl * 4) >> 3) ^ (r & 7)) << 4) + ((cl & 1) ? 8 : 0);
  }
  const int wrow = tid >> 3, wg = tid & 7;
  const unsigned short* wptr = WuT + (size_t)(n0 + wrow) * Hh + wg * 8;
  int wwr[8];
#pragma unroll
  for (int it = 0; it < 8; ++it) {
    int n = wrow + it * 32;
    wwr[it] = n * 128 + ((wg ^ (n & 7)) << 4);
  }

  const int lane = tid & 63, wave = tid >> 6;
  const int wm = wave >> 1, wn = wave & 1;
  const int lr = lane & 15, lq = lane >> 4;
  int ard[2][2];
#pragma unroll
  for (int mf = 0; mf < 2; ++mf)
#pragma unroll
    for (int kf = 0; kf < 2; ++kf) {
      int r = wm * 32 + mf * 16 + lr;
      ard[mf][kf] = r * 128 + (((kf * 4 + lq) ^ (r & 7)) << 4);
    }
  int brd[8][2];
#pragma unroll
  for (int nf = 0; nf < 8; ++nf)
#pragma unroll
    for (int kf = 0; kf < 2; ++kf) {
      int n = wn * 128 + nf * 16 + lr;
      brd[nf][kf] = n * 128 + (((kf * 4 + lq) ^ (n & 7)) << 4);
    }

  f32x4 acc[2][8] = {};
  float sacc[4] = {0.f, 0.f, 0.f, 0.f};

  for (int ks = 0; ks < 4; ++ks) {
    __syncthreads();
#pragma unroll
    for (int j = 0; j < 4; ++j) {
      u16x4 v = *(const u16x4*)(aptr + (size_t)j * 16 * Hh);
      sacc[j] += bf2f(v[0]) + bf2f(v[1]) + bf2f(v[2]) + bf2f(v[3]);
      *(u16x4*)(As + aw[j]) = v;
    }
    aptr += 64;
#pragma unroll
    for (int it = 0; it < 8; ++it) {
      s16x8 w = *(const s16x8*)(wptr + (size_t)it * 32 * Hh);
      *(s16x8*)(Ws + wwr[it]) = w;
    }
    wptr += 64;
    __syncthreads();
#pragma unroll
    for (int kf = 0; kf < 2; ++kf) {
      s16x8 a0 = *(const s16x8*)(As + ard[0][kf]);
      s16x8 a1 = *(const s16x8*)(As + ard[1][kf]);
#pragma unroll
      for (int nf = 0; nf < 8; ++nf) {
        s16x8 bb = *(const s16x8*)(Ws + brd[nf][kf]);
        acc[0][nf] = __builtin_amdgcn_mfma_f32_16x16x32_bf16(a0, bb, acc[0][nf], 0, 0, 0);
        acc[1][nf] = __builtin_amdgcn_mfma_f32_16x16x32_bf16(a1, bb, acc[1][nf], 0, 0, 0);
      }
    }
  }

#pragma unroll
  for (int j = 0; j < 4; ++j) {
    float s = sacc[j];
    s += __shfl_xor(s, 1); s += __shfl_xor(s, 2); s += __shfl_xor(s, 4); s += __shfl_xor(s, 8);
    if (lr == 0) asum[rowg + j * 16] = s;
  }
  __syncthreads();

#pragma unroll
  for (int mf = 0; mf < 2; ++mf) {
    int rbase = wm * 32 + mf * 16 + lq * 4;
#pragma unroll
    for (int nf = 0; nf < 8; ++nf) {
      int dn = wn * 128 + nf * 16 + lr;
      float ugv = ugs[dn], ubv = ubs[dn];
#pragma unroll
      for (int j = 0; j < 4; ++j) {
        size_t gi = (size_t)(row0 + rbase + j) * Dd + n0 + dn;
        float v = acc[mf][nf][j] * ugv + ubv * asum[rbase + j] + X[gi];
        out[gi] = v;
      }
    }
  }
}

extern "C" void kernel_launch(void* const* d_in, const int* in_sizes, int n_in,
                              void* d_out, int out_size, void* d_ws, size_t ws_size,
                              hipStream_t stream) {
  const float* hidden       = (const float*)d_in[0];
  const float* conditions   = (const float*)d_in[1];
  const float* down_project = (const float*)d_in[2];
  const float* down_gamma   = (const float*)d_in[3];
  const float* down_beta    = (const float*)d_in[4];
  const float* up_project   = (const float*)d_in[5];
  const float* up_gamma     = (const float*)d_in[6];
  const float* up_beta      = (const float*)d_in[7];
  float* out = (float*)d_out;

  char* ws = (char*)d_ws;
  float* coef = (float*)ws;
  unsigned short* WdT  = (unsigned short*)(ws + WDT_BYTE);
  unsigned short* WuT  = (unsigned short*)(ws + WUT_BYTE);
  unsigned short* actb = (unsigned short*)(ws + ACT_BYTE);

  coef_kernel<<<80, 256, 0, stream>>>(conditions, down_gamma, down_beta, up_gamma, up_beta, coef);
  transpose_kernel<<<256, 256, 0, stream>>>(down_project, WdT, 1024, 256);  // Wd [1024,256] -> WdT [256,1024]
  transpose_kernel<<<256, 256, 0, stream>>>(up_project,  WuT, 256, 1024);   // Wu [256,1024] -> WuT [1024,256]
  gemm1_kernel<<<512, 256, 0, stream>>>(hidden, WdT, coef, actb);
  gemm2_kernel<<<dim3(512, 4), 256, 0, stream>>>(actb, WuT, coef, hidden, out);
}

// Round 2
// 111.483 us; speedup vs baseline: 1.1417x; 1.1417x over previous
//
#include <hip/hip_runtime.h>
#include <hip/hip_bf16.h>

typedef __attribute__((ext_vector_type(4))) float f32x4;
typedef __attribute__((ext_vector_type(8))) short s16x8;
typedef __attribute__((ext_vector_type(8))) unsigned short u16x8;
typedef __attribute__((ext_vector_type(2))) unsigned int u32x2;

#define DEVFN static __device__ __forceinline__

DEVFN unsigned short f2bf(float f) {
  union { float f; unsigned int u; } v; v.f = f;
  unsigned int u = v.u;
  u += 0x7fffu + ((u >> 16) & 1u);   // RNE
  return (unsigned short)(u >> 16);
}

DEVFN unsigned int cvt_pk(float a, float b) {
  __hip_bfloat162 h = __float22bfloat162_rn(make_float2(a, b));
  union { __hip_bfloat162 h; unsigned int u; } v; v.h = h; return v.u;
}

DEVFN void gl_lds16(const void* g, void* l) {
  __builtin_amdgcn_global_load_lds((__attribute__((address_space(1))) void*)g,
                                   (__attribute__((address_space(3))) void*)l, 16, 0, 0);
}

// ws layout (bytes)
#define DG_OFF 0
#define DB_OFF 2048
#define UG_OFF 4096
#define UB_OFF 12288
#define W1_BYTE   81920      // [2 ntile][16 kc][128 n][64 k] bf16 swizzled  (512 KB)
#define W2_BYTE   606208     // [8 ntile][4 kc][128 n][64 k] bf16 swizzled   (512 KB)
#define ASUM_BYTE 1130496    // float asum_part[2][32768]                    (256 KB)
#define ACT_BYTE  1392640    // [256 mtile][4 kc][128 r][64 k] bf16 swizzled (16 MB)

// ---------- coefficient GEMMs: conditions[8,512] @ {gamma,beta} ----------
__global__ void coef_kernel(const float* __restrict__ cond,
                            const float* __restrict__ dgm, const float* __restrict__ dbt,
                            const float* __restrict__ ugm, const float* __restrict__ ubt,
                            float* __restrict__ coef) {
  __shared__ float lc[4096];
  __shared__ float red[2048];
  const int t = threadIdx.x;
#pragma unroll
  for (int i = 0; i < 16; ++i) lc[t + i * 256] = cond[t + i * 256];
  __syncthreads();
  const int col = blockIdx.x * 16 + (t & 15);
  const int ks = t >> 4;
  const float* src; int ncol, cl;
  if (col < 256)       { src = dgm; ncol = 256;  cl = col; }
  else if (col < 512)  { src = dbt; ncol = 256;  cl = col - 256; }
  else if (col < 1536) { src = ugm; ncol = 1024; cl = col - 512; }
  else                 { src = ubt; ncol = 1024; cl = col - 1536; }
  float acc[8] = {};
  for (int k = ks * 32; k < ks * 32 + 32; ++k) {
    float g = src[(size_t)k * ncol + cl];
#pragma unroll
    for (int b = 0; b < 8; ++b) acc[b] = fmaf(lc[b * 512 + k], g, acc[b]);
  }
#pragma unroll
  for (int b = 0; b < 8; ++b) red[(ks * 16 + (t & 15)) * 8 + b] = acc[b];
  __syncthreads();
  if (t < 128) {
    int c = t >> 3, b = t & 7;
    float s = 0.f;
#pragma unroll
    for (int k2 = 0; k2 < 16; ++k2) s += red[(k2 * 16 + c) * 8 + b];
    int colg = blockIdx.x * 16 + c;
    float* dst; int ncol2, cl2;
    if (colg < 256)       { dst = coef + DG_OFF; ncol2 = 256;  cl2 = colg; }
    else if (colg < 512)  { dst = coef + DB_OFF; ncol2 = 256;  cl2 = colg - 256; }
    else if (colg < 1536) { dst = coef + UG_OFF; ncol2 = 1024; cl2 = colg - 512; }
    else                  { dst = coef + UB_OFF; ncol2 = 1024; cl2 = colg - 1536; }
    dst[b * ncol2 + cl2] = s;
  }
}

// ---------- build pre-swizzled bf16 weight images ----------
// image chunk = [128 n][64 k] bf16, 16B granule g at byte n*128 + ((g^(n&7))<<4)
__global__ void wimg_kernel(const float* __restrict__ Wd, const float* __restrict__ Wu,
                            char* __restrict__ ws) {
  const int bid = blockIdx.x;
  const float* src; char* dst; int C, ntile, kc;
  if (bid < 32) { src = Wd; C = 256;  ntile = bid >> 4; kc = bid & 15;
                  dst = ws + W1_BYTE + (size_t)(ntile * 16 + kc) * 16384; }
  else { int b2 = bid - 32; src = Wu; C = 1024; ntile = b2 >> 2; kc = b2 & 3;
         dst = ws + W2_BYTE + (size_t)(ntile * 4 + kc) * 16384; }
  const int t = threadIdx.x;
  const int n = t >> 1, kh = t & 1;
  const float* sp = src + (size_t)(kc * 64 + kh * 32) * C + ntile * 128 + n;
  unsigned short tmp[32];
#pragma unroll
  for (int kk = 0; kk < 32; ++kk) tmp[kk] = f2bf(sp[(size_t)kk * C]);
  char* drow = dst + n * 128;
#pragma unroll
  for (int gi = 0; gi < 4; ++gi) {
    u16x8 v;
#pragma unroll
    for (int e = 0; e < 8; ++e) v[e] = tmp[gi * 8 + e];
    int g = kh * 4 + gi;
    *(u16x8*)(drow + ((g ^ (n & 7)) << 4)) = v;
  }
}

// ---------- GEMM1: act_img = relu(dg ∘ (X @ Wd) + db ∘ rowsum(X)) ----------
// BM=128, BN=128 (ntile of H=256), BK=64, 4 waves (2m x 2n), wave tile 64x64
__global__ __launch_bounds__(256, 2)
void gemm1_kernel(const float* __restrict__ X, char* __restrict__ ws) {
  __shared__ char lds[65536];   // Xs0/Xs1 @0/16K, Ws0/Ws1 @32K/48K
  const int tid = threadIdx.x;
  const int lane = tid & 63, wave = tid >> 6;
  const int lr = lane & 15, lq = lane >> 4;
  const int wm = wave >> 1, wn = wave & 1;

  const int raw = blockIdx.x;
  const int swz = (raw & 7) * 64 + (raw >> 3);      // XCD-chunked, 512 % 8 == 0
  const int m = swz >> 1, ntile = swz & 1;
  const int row0 = m << 7;
  const int b = m >> 5;

  const float* coef = (const float*)ws;
  const char* w1img = ws + W1_BYTE + (size_t)(ntile * 16) * 16384;
  float* asump = (float*)(ws + ASUM_BYTE);

  // staging: thread covers rows srow+16j, cols scol*4..+3 of the [128][64] chunk
  const int srow = tid >> 4, scol = tid & 15;
  const float* xptr = X + (size_t)(row0 + srow) * 1024 + scol * 4;
  int xw[8];
#pragma unroll
  for (int j = 0; j < 8; ++j) {
    int r = srow + 16 * j;
    xw[j] = r * 128 + (((scol >> 1) ^ (r & 7)) << 4) + ((scol & 1) ? 8 : 0);
  }
  int aoff[4][2], boff[4][2];
#pragma unroll
  for (int mf = 0; mf < 4; ++mf)
#pragma unroll
    for (int kf = 0; kf < 2; ++kf) {
      int r = wm * 64 + mf * 16 + lr;
      aoff[mf][kf] = r * 128 + (((kf * 4 + lq) ^ (r & 7)) << 4);
    }
#pragma unroll
  for (int nf = 0; nf < 4; ++nf)
#pragma unroll
    for (int kf = 0; kf < 2; ++kf) {
      int n = wn * 64 + nf * 16 + lr;
      boff[nf][kf] = n * 128 + (((kf * 4 + lq) ^ (n & 7)) << 4);
    }

  f32x4 acc[4][4] = {};
  float hacc[8] = {};
  f32x4 xv[8];

  // prologue: stage kc=0 into buf0
#pragma unroll
  for (int i = 0; i < 4; ++i)
    gl_lds16(w1img + (wave * 4 + i) * 1024 + lane * 16, lds + 32768 + (wave * 4 + i) * 1024);
#pragma unroll
  for (int j = 0; j < 8; ++j) xv[j] = *(const f32x4*)(xptr + (size_t)(16 * j) * 1024);
#pragma unroll
  for (int j = 0; j < 8; ++j) {
    hacc[j] += xv[j][0] + xv[j][1] + xv[j][2] + xv[j][3];
    u32x2 p; p[0] = cvt_pk(xv[j][0], xv[j][1]); p[1] = cvt_pk(xv[j][2], xv[j][3]);
    *(u32x2*)(lds + xw[j]) = p;
  }
  __syncthreads();

  for (int t = 0; t < 16; ++t) {
    const int cur = t & 1, nxt = cur ^ 1;
    if (t < 15) {
      const char* wsrc = w1img + (size_t)(t + 1) * 16384;
#pragma unroll
      for (int i = 0; i < 4; ++i)
        gl_lds16(wsrc + (wave * 4 + i) * 1024 + lane * 16,
                 lds + 32768 + nxt * 16384 + (wave * 4 + i) * 1024);
      const float* xs = xptr + (t + 1) * 64;
#pragma unroll
      for (int j = 0; j < 8; ++j) xv[j] = *(const f32x4*)(xs + (size_t)(16 * j) * 1024);
    }
    const char* Xc = lds + cur * 16384;
    const char* Wc = lds + 32768 + cur * 16384;
#pragma unroll
    for (int kf = 0; kf < 2; ++kf) {
      s16x8 a[4], bb[4];
#pragma unroll
      for (int mf = 0; mf < 4; ++mf) a[mf] = *(const s16x8*)(Xc + aoff[mf][kf]);
#pragma unroll
      for (int nf = 0; nf < 4; ++nf) bb[nf] = *(const s16x8*)(Wc + boff[nf][kf]);
#pragma unroll
      for (int mf = 0; mf < 4; ++mf)
#pragma unroll
        for (int nf = 0; nf < 4; ++nf)
          acc[mf][nf] = __builtin_amdgcn_mfma_f32_16x16x32_bf16(a[mf], bb[nf], acc[mf][nf], 0, 0, 0);
    }
    if (t < 15) {
      char* Xn = lds + nxt * 16384;
#pragma unroll
      for (int j = 0; j < 8; ++j) {
        hacc[j] += xv[j][0] + xv[j][1] + xv[j][2] + xv[j][3];
        u32x2 p; p[0] = cvt_pk(xv[j][0], xv[j][1]); p[1] = cvt_pk(xv[j][2], xv[j][3]);
        *(u32x2*)(Xn + xw[j]) = p;
      }
    }
    __syncthreads();
  }

  // ---- epilogue ----
  float* hsumb = (float*)lds;           // 128 f32
  float* asumb = (float*)(lds + 1024);  // 2*128 f32
#pragma unroll
  for (int j = 0; j < 8; ++j) {
    float s = hacc[j];
    s += __shfl_xor(s, 1); s += __shfl_xor(s, 2); s += __shfl_xor(s, 4); s += __shfl_xor(s, 8);
    if (lr == 0) hsumb[wave * 4 + lq + 16 * j] = s;
  }
  __syncthreads();

  float dgv[4], dbv[4];
#pragma unroll
  for (int nf = 0; nf < 4; ++nf) {
    int h = ntile * 128 + wn * 64 + nf * 16 + lr;
    dgv[nf] = coef[DG_OFF + b * 256 + h];
    dbv[nf] = coef[DB_OFF + b * 256 + h];
  }

  char* actb = ws + ACT_BYTE + (size_t)m * 65536;
  float asacc[4][4] = {};
#pragma unroll
  for (int nf = 0; nf < 4; ++nf) {
    int hfull = ntile * 128 + wn * 64 + nf * 16 + lr;
    int kc = hfull >> 6, kl = hfull & 63;
    int g = kl >> 3, gb = (kl & 7) * 2;
    char* nbase = actb + kc * 16384 + gb;
    float dg_ = dgv[nf], db_ = dbv[nf];
#pragma unroll
    for (int mf = 0; mf < 4; ++mf) {
      int rb = wm * 64 + mf * 16 + lq * 4;
#pragma unroll
      for (int j = 0; j < 4; ++j) {
        int r = rb + j;
        float v = acc[mf][nf][j] * dg_ + db_ * hsumb[r];
        v = fmaxf(v, 0.f);
        asacc[mf][j] += v;
        *(unsigned short*)(nbase + r * 128 + ((g ^ (r & 7)) << 4)) = f2bf(v);
      }
    }
  }
#pragma unroll
  for (int mf = 0; mf < 4; ++mf)
#pragma unroll
    for (int j = 0; j < 4; ++j) {
      float s = asacc[mf][j];
      s += __shfl_xor(s, 1); s += __shfl_xor(s, 2); s += __shfl_xor(s, 4); s += __shfl_xor(s, 8);
      if (lr == 0) asumb[wn * 128 + wm * 64 + mf * 16 + lq * 4 + j] = s;
    }
  __syncthreads();
  if (tid < 128) asump[ntile * 32768 + row0 + tid] = asumb[tid] + asumb[128 + tid];
}

// ---------- GEMM2: out = ug ∘ (act @ Wu) + ub ∘ rowsum(act) + X ----------
// BM=128, BN=128 (8 ntiles of D=1024), BK=64, K=256, both operands via global_load_lds
__global__ __launch_bounds__(256, 2)
void gemm2_kernel(const float* __restrict__ X, const char* __restrict__ ws,
                  float* __restrict__ out) {
  __shared__ char lds[65536];
  const int tid = threadIdx.x;
  const int lane = tid & 63, wave = tid >> 6;
  const int lr = lane & 15, lq = lane >> 4;
  const int wm = wave >> 1, wn = wave & 1;

  const int raw = blockIdx.x;
  const int swz = (raw & 7) * 256 + (raw >> 3);     // 2048 % 8 == 0
  const int m = swz >> 3, nt = swz & 7;
  const int row0 = m << 7, n0 = nt << 7;
  const int b = m >> 5;

  const float* coef = (const float*)ws;
  const char* aimg = ws + ACT_BYTE + (size_t)m * 65536;
  const char* wimg = ws + W2_BYTE + (size_t)(nt * 4) * 16384;
  const float* asump = (const float*)(ws + ASUM_BYTE);

  int aoff[4][2], boff[4][2];
#pragma unroll
  for (int mf = 0; mf < 4; ++mf)
#pragma unroll
    for (int kf = 0; kf < 2; ++kf) {
      int r = wm * 64 + mf * 16 + lr;
      aoff[mf][kf] = r * 128 + (((kf * 4 + lq) ^ (r & 7)) << 4);
    }
#pragma unroll
  for (int nf = 0; nf < 4; ++nf)
#pragma unroll
    for (int kf = 0; kf < 2; ++kf) {
      int n = wn * 64 + nf * 16 + lr;
      boff[nf][kf] = n * 128 + (((kf * 4 + lq) ^ (n & 7)) << 4);
    }

  f32x4 acc[4][4] = {};

#pragma unroll
  for (int i = 0; i < 4; ++i) {
    gl_lds16(aimg + (wave * 4 + i) * 1024 + lane * 16, lds + (wave * 4 + i) * 1024);
    gl_lds16(wimg + (wave * 4 + i) * 1024 + lane * 16, lds + 32768 + (wave * 4 + i) * 1024);
  }
  __syncthreads();

  for (int t = 0; t < 4; ++t) {
    const int cur = t & 1, nxt = cur ^ 1;
    if (t < 3) {
#pragma unroll
      for (int i = 0; i < 4; ++i) {
        gl_lds16(aimg + (size_t)(t + 1) * 16384 + (wave * 4 + i) * 1024 + lane * 16,
                 lds + nxt * 16384 + (wave * 4 + i) * 1024);
        gl_lds16(wimg + (size_t)(t + 1) * 16384 + (wave * 4 + i) * 1024 + lane * 16,
                 lds + 32768 + nxt * 16384 + (wave * 4 + i) * 1024);
      }
    }
    const char* Ac = lds + cur * 16384;
    const char* Wc = lds + 32768 + cur * 16384;
#pragma unroll
    for (int kf = 0; kf < 2; ++kf) {
      s16x8 a[4], bb[4];
#pragma unroll
      for (int mf = 0; mf < 4; ++mf) a[mf] = *(const s16x8*)(Ac + aoff[mf][kf]);
#pragma unroll
      for (int nf = 0; nf < 4; ++nf) bb[nf] = *(const s16x8*)(Wc + boff[nf][kf]);
#pragma unroll
      for (int mf = 0; mf < 4; ++mf)
#pragma unroll
        for (int nf = 0; nf < 4; ++nf)
          acc[mf][nf] = __builtin_amdgcn_mfma_f32_16x16x32_bf16(a[mf], bb[nf], acc[mf][nf], 0, 0, 0);
    }
    __syncthreads();
  }

  float ugv[4], ubv[4];
#pragma unroll
  for (int nf = 0; nf < 4; ++nf) {
    int d = n0 + wn * 64 + nf * 16 + lr;
    ugv[nf] = coef[UG_OFF + b * 1024 + d];
    ubv[nf] = coef[UB_OFF + b * 1024 + d];
  }
#pragma unroll
  for (int mf = 0; mf < 4; ++mf) {
#pragma unroll
    for (int j = 0; j < 4; ++j) {
      int r = row0 + wm * 64 + mf * 16 + lq * 4 + j;
      float as = asump[r] + asump[32768 + r];
      size_t rowb = (size_t)r * 1024;
#pragma unroll
      for (int nf = 0; nf < 4; ++nf) {
        size_t gi = rowb + n0 + wn * 64 + nf * 16 + lr;
        out[gi] = acc[mf][nf][j] * ugv[nf] + ubv[nf] * as + X[gi];
      }
    }
  }
}

extern "C" void kernel_launch(void* const* d_in, const int* in_sizes, int n_in,
                              void* d_out, int out_size, void* d_ws, size_t ws_size,
                              hipStream_t stream) {
  const float* hidden       = (const float*)d_in[0];
  const float* conditions   = (const float*)d_in[1];
  const float* down_project = (const float*)d_in[2];
  const float* down_gamma   = (const float*)d_in[3];
  const float* down_beta    = (const float*)d_in[4];
  const float* up_project   = (const float*)d_in[5];
  const float* up_gamma     = (const float*)d_in[6];
  const float* up_beta      = (const float*)d_in[7];
  float* out = (float*)d_out;
  char* ws = (char*)d_ws;

  coef_kernel<<<160, 256, 0, stream>>>(conditions, down_gamma, down_beta, up_gamma, up_beta,
                                       (float*)ws);
  wimg_kernel<<<64, 256, 0, stream>>>(down_project, up_project, ws);
  gemm1_kernel<<<512, 256, 0, stream>>>(hidden, ws);
  gemm2_kernel<<<2048, 256, 0, stream>>>(hidden, ws, out);
}